// Round 5
// baseline (415.326 us; speedup 1.0000x reference)
//
#include <hip/hip_runtime.h>
#include <math.h>

static constexpr int NNODES = 50000;
static constexpr int NEDGES = 600000;
static constexpr int D = 128;
static constexpr int NPART = (NNODES + 255) / 256;  // 196

typedef __attribute__((ext_vector_type(8))) short short8;   // 8 bf16 in 4 VGPRs
typedef __attribute__((ext_vector_type(4))) float f32x4;

static __device__ inline unsigned short f2bf_rne(float f) {
  unsigned u = __float_as_uint(f);
  unsigned r = (u + 0x7FFFu + ((u >> 16) & 1u)) >> 16;
  return (unsigned short)r;
}
static __device__ inline float bf2f(unsigned short s) {
  return __uint_as_float(((unsigned)s) << 16);
}

// ---------------- x -> bf16 hi/lo split ----------------
__global__ __launch_bounds__(256) void split_kernel(const float* __restrict__ x,
    unsigned short* __restrict__ hi, unsigned short* __restrict__ lo, int n4) {
  int i = blockIdx.x * 256 + threadIdx.x;
  if (i >= n4) return;
  f32x4 v = *(const f32x4*)(x + (size_t)i * 4);
  ushort4 h, l;
  h.x = f2bf_rne(v[0]); l.x = f2bf_rne(v[0] - bf2f(h.x));
  h.y = f2bf_rne(v[1]); l.y = f2bf_rne(v[1] - bf2f(h.y));
  h.z = f2bf_rne(v[2]); l.z = f2bf_rne(v[2] - bf2f(h.z));
  h.w = f2bf_rne(v[3]); l.w = f2bf_rne(v[3] - bf2f(h.w));
  *(ushort4*)(hi + (size_t)i * 4) = h;
  *(ushort4*)(lo + (size_t)i * 4) = l;
}

// ---------------- CSR build ----------------

__global__ void count_kernel(const int* __restrict__ dst, int* __restrict__ cnt, int nE) {
  int i = blockIdx.x * blockDim.x + threadIdx.x;
  if (i < nE) atomicAdd(&cnt[dst[i]], 1);
}

__global__ void scan_partial(const int* __restrict__ cnt, int* __restrict__ part, int n) {
  int i = blockIdx.x * 256 + threadIdx.x;
  int v = (i < n) ? cnt[i] : 0;
#pragma unroll
  for (int off = 32; off > 0; off >>= 1) v += __shfl_down(v, off);
  __shared__ int ws[4];
  int wid = threadIdx.x >> 6, lane = threadIdx.x & 63;
  if (lane == 0) ws[wid] = v;
  __syncthreads();
  if (threadIdx.x == 0) part[blockIdx.x] = ws[0] + ws[1] + ws[2] + ws[3];
}

__global__ void scan_root(const int* __restrict__ part, int* __restrict__ pscan,
                          int* __restrict__ rs_last, int np) {
  int i = threadIdx.x;                 // single block, 256 threads, np <= 256
  int v = (i < np) ? part[i] : 0;
  int incl = v;
  int lane = i & 63, wid = i >> 6;
#pragma unroll
  for (int off = 1; off < 64; off <<= 1) {
    int t = __shfl_up(incl, off);
    if (lane >= off) incl += t;
  }
  __shared__ int ws[4];
  if (lane == 63) ws[wid] = incl;
  __syncthreads();
  int woff = 0;
  for (int w = 0; w < wid; ++w) woff += ws[w];
  if (i < np) pscan[i] = woff + incl - v;  // exclusive
  if (i == 0) *rs_last = ws[0] + ws[1] + ws[2] + ws[3];
}

__global__ void scan_apply(const int* __restrict__ cnt, const int* __restrict__ pscan,
                           int* __restrict__ rs, int* __restrict__ cursor, int n) {
  int i = blockIdx.x * 256 + threadIdx.x;
  int v = (i < n) ? cnt[i] : 0;
  int incl = v;
  int lane = threadIdx.x & 63, wid = threadIdx.x >> 6;
#pragma unroll
  for (int off = 1; off < 64; off <<= 1) {
    int t = __shfl_up(incl, off);
    if (lane >= off) incl += t;
  }
  __shared__ int ws[4];
  if (lane == 63) ws[wid] = incl;
  __syncthreads();
  int woff = pscan[blockIdx.x];
  for (int w = 0; w < wid; ++w) woff += ws[w];
  int ex = woff + incl - v;
  if (i < n) { rs[i] = ex; cursor[i] = ex; }
}

__global__ void fill_kernel(const int* __restrict__ src, const int* __restrict__ dst,
                            int* __restrict__ cursor, int* __restrict__ csr, int nE) {
  int i = blockIdx.x * blockDim.x + threadIdx.x;
  if (i < nE) {
    int d = dst[i];
    int p = atomicAdd(&cursor[d], 1);
    csr[p] = src[i];
  }
}

// ---------------- segment-max aggregation (bf16 gather, CSR, no atomics) ----------------
// One wave per destination node; lane owns 2 bf16 features (one uint); max in f32 domain.
// Output uint is exact bf16 pair (max of bf16 values is a bf16 value).
__global__ __launch_bounds__(256) void agg_kernel(const unsigned int* __restrict__ xb,
    const int* __restrict__ rs, const int* __restrict__ csr,
    unsigned int* __restrict__ aggb, int n) {
  int gw = (int)((blockIdx.x * blockDim.x + threadIdx.x) >> 6);
  int lane = threadIdx.x & 63;
  if (gw >= n) return;
  int beg = rs[gw], end = rs[gw + 1];
  float ax = -INFINITY, ay = -INFINITY;
  int j = beg;
  for (; j + 8 <= end; j += 8) {
    int s[8];
#pragma unroll
    for (int u = 0; u < 8; ++u) s[u] = csr[j + u];
    unsigned v[8];
#pragma unroll
    for (int u = 0; u < 8; ++u) v[u] = xb[(size_t)s[u] * 64 + lane];
#pragma unroll
    for (int u = 0; u < 8; ++u) {
      ax = fmaxf(ax, bf2f((unsigned short)(v[u] & 0xFFFFu)));
      ay = fmaxf(ay, bf2f((unsigned short)(v[u] >> 16)));
    }
  }
  for (; j < end; ++j) {
    unsigned v = xb[(size_t)csr[j] * 64 + lane];
    ax = fmaxf(ax, bf2f((unsigned short)(v & 0xFFFFu)));
    ay = fmaxf(ay, bf2f((unsigned short)(v >> 16)));
  }
  if (beg == end) { ax = 0.f; ay = 0.f; }  // isolated node -> 0 (PyG fill)
  aggb[(size_t)gw * 64 + lane] =
      (__float_as_uint(ax) >> 16) | (__float_as_uint(ay) & 0xFFFF0000u);
}

// ---------------- weight pre-pack into MFMA B-fragment layout ----------------
// B-fragment (16x16x32): lane l holds B[k = ks*32 + (l>>4)*8 + e][j = jb*16 + (l&15)]
// Packed flat index: ((jb*4 + ks)*64 + lane)*8 + e -> per-lane 16B coalesced loads.
struct PackArgs {
  const float* src[4];
  unsigned short* hi[4];
  unsigned short* lo[4];
};

__global__ void pack_all(PackArgs pa) {
  int mat = blockIdx.x >> 3;                       // 0..3
  int tid = (blockIdx.x & 7) * 256 + threadIdx.x;  // 0..2047
  const float* Wm = pa.src[mat];
  unsigned short* hi = pa.hi[mat];
  unsigned short* lo = pa.lo[mat];
  int jb = tid >> 8;
  int ks = (tid >> 6) & 3;
  int lane = tid & 63;
  int j = jb * 16 + (lane & 15);
  int k0 = ks * 32 + (lane >> 4) * 8;
#pragma unroll
  for (int e = 0; e < 8; ++e) {
    float v = Wm[(k0 + e) * D + j];
    unsigned short h = f2bf_rne(v);
    float rem = v - bf2f(h);
    unsigned short l = f2bf_rne(rem);
    hi[tid * 8 + e] = h;
    lo[tid * 8 + e] = l;
  }
}

// ---------------- fused dual-GEMM + bias + relu (bf16 MFMA, hi/lo split) ----------------
// out = relu(agg@W + h@R + b). 4 waves/block, 32 rows/wave (2 groups of 16), no LDS.
// agg is exact bf16 (lo==0): agg@W = agg@Whi + agg@Wlo (2 MFMA).
// h = hhi + hlo:            h@R  = hhi@Rhi + hlo@Rhi + hhi@Rlo (3 MFMA).
// Epilogue: final layer -> f32 to outf; mid layers -> bf16 hi/lo pair (ohi, olo).
__global__ __launch_bounds__(256) void gemm_mfma(
    const unsigned short* __restrict__ aggb,
    const unsigned short* __restrict__ hhi, const unsigned short* __restrict__ hlo,
    const unsigned short* __restrict__ Whi, const unsigned short* __restrict__ Wlo,
    const unsigned short* __restrict__ Rhi, const unsigned short* __restrict__ Rlo,
    const float* __restrict__ bias, float* __restrict__ outf,
    unsigned short* __restrict__ ohi, unsigned short* __restrict__ olo, int nrows) {
  const int lane = threadIdx.x & 63;
  const int wv = threadIdx.x >> 6;       // 0..3
  const int m_lo = lane & 15;
  const int kgrp = lane >> 4;            // 0..3
  const int r_base = blockIdx.x * 128 + wv * 32;

  f32x4 acc[2][8];
#pragma unroll
  for (int g = 0; g < 2; ++g)
#pragma unroll
    for (int jb = 0; jb < 8; ++jb) acc[g][jb] = (f32x4)0.f;

  float bv[8];
#pragma unroll
  for (int jb = 0; jb < 8; ++jb) bv[jb] = bias[jb * 16 + m_lo];

  for (int ks = 0; ks < 4; ++ks) {
    short8 fa[2], fhh[2], fhl[2];
#pragma unroll
    for (int g = 0; g < 2; ++g) {
      int row = r_base + g * 16 + m_lo;
      if (row >= nrows) row = nrows - 1;
      const size_t ro = (size_t)row * D + ks * 32 + kgrp * 8;
      fa[g]  = *(const short8*)(aggb + ro);
      fhh[g] = *(const short8*)(hhi + ro);
      fhl[g] = *(const short8*)(hlo + ro);
    }
#pragma unroll
    for (int jb = 0; jb < 8; ++jb) {
      const int pidx = ((jb * 4 + ks) * 64 + lane) * 8;
      short8 bwhi = *(const short8*)(Whi + pidx);
      short8 bwlo = *(const short8*)(Wlo + pidx);
      short8 brhi = *(const short8*)(Rhi + pidx);
      short8 brlo = *(const short8*)(Rlo + pidx);
#pragma unroll
      for (int g = 0; g < 2; ++g) {
        acc[g][jb] = __builtin_amdgcn_mfma_f32_16x16x32_bf16(fa[g],  bwhi, acc[g][jb], 0, 0, 0);
        acc[g][jb] = __builtin_amdgcn_mfma_f32_16x16x32_bf16(fa[g],  bwlo, acc[g][jb], 0, 0, 0);
        acc[g][jb] = __builtin_amdgcn_mfma_f32_16x16x32_bf16(fhh[g], brhi, acc[g][jb], 0, 0, 0);
        acc[g][jb] = __builtin_amdgcn_mfma_f32_16x16x32_bf16(fhl[g], brhi, acc[g][jb], 0, 0, 0);
        acc[g][jb] = __builtin_amdgcn_mfma_f32_16x16x32_bf16(fhh[g], brlo, acc[g][jb], 0, 0, 0);
      }
    }
  }

  // D layout: col = lane&15, row-in-tile = kgrp*4 + reg
#pragma unroll
  for (int g = 0; g < 2; ++g) {
#pragma unroll
    for (int jb = 0; jb < 8; ++jb) {
#pragma unroll
      for (int r = 0; r < 4; ++r) {
        int row = r_base + g * 16 + kgrp * 4 + r;
        if (row < nrows) {
          float v = fmaxf(acc[g][jb][r] + bv[jb], 0.f);
          size_t o = (size_t)row * D + jb * 16 + m_lo;
          if (outf) {
            outf[o] = v;
          } else {
            unsigned short h = f2bf_rne(v);
            ohi[o] = h;
            olo[o] = f2bf_rne(v - bf2f(h));
          }
        }
      }
    }
  }
}

// ---------------- launch ----------------

extern "C" void kernel_launch(void* const* d_in, const int* in_sizes, int n_in,
                              void* d_out, int out_size, void* d_ws, size_t ws_size,
                              hipStream_t stream) {
  const float* x  = (const float*)d_in[0];
  const int*   ei = (const int*)d_in[1];
  const float* W1 = (const float*)d_in[2];
  const float* b1 = (const float*)d_in[3];
  const float* R1 = (const float*)d_in[4];
  const float* W2 = (const float*)d_in[5];
  const float* b2 = (const float*)d_in[6];
  const float* R2 = (const float*)d_in[7];
  float* out = (float*)d_out;

  const int* src = ei;
  const int* dst = ei + NEDGES;

  char* ws = (char*)d_ws;
  size_t off = 0;
  auto alloc = [&](size_t bytes) -> void* {
    off = (off + 511) & ~(size_t)511;
    void* p = ws + off;
    off += bytes;
    return p;
  };
  const size_t NF = (size_t)NNODES * D;  // 6.4M elements
  unsigned short* xhi  = (unsigned short*)alloc(sizeof(short) * NF);
  unsigned short* xlo  = (unsigned short*)alloc(sizeof(short) * NF);
  unsigned short* hAhi = (unsigned short*)alloc(sizeof(short) * NF);
  unsigned short* hAlo = (unsigned short*)alloc(sizeof(short) * NF);
  unsigned short* hBhi = (unsigned short*)alloc(sizeof(short) * NF);
  unsigned short* hBlo = (unsigned short*)alloc(sizeof(short) * NF);
  unsigned short* aggb = (unsigned short*)alloc(sizeof(short) * NF);
  int* cnt    = (int*)alloc(sizeof(int) * NNODES);
  int* rs     = (int*)alloc(sizeof(int) * (NNODES + 1));
  int* cursor = (int*)alloc(sizeof(int) * NNODES);
  int* csr    = (int*)alloc(sizeof(int) * NEDGES);
  int* part   = (int*)alloc(sizeof(int) * NPART);
  int* pscan  = (int*)alloc(sizeof(int) * NPART);
  const int PACKN = 2048 * 8;  // 16384 bf16 per matrix
  unsigned short* w1hi = (unsigned short*)alloc(sizeof(short) * PACKN);
  unsigned short* w1lo = (unsigned short*)alloc(sizeof(short) * PACKN);
  unsigned short* r1hi = (unsigned short*)alloc(sizeof(short) * PACKN);
  unsigned short* r1lo = (unsigned short*)alloc(sizeof(short) * PACKN);
  unsigned short* w2hi = (unsigned short*)alloc(sizeof(short) * PACKN);
  unsigned short* w2lo = (unsigned short*)alloc(sizeof(short) * PACKN);
  unsigned short* r2hi = (unsigned short*)alloc(sizeof(short) * PACKN);
  unsigned short* r2lo = (unsigned short*)alloc(sizeof(short) * PACKN);

  // x -> bf16 hi/lo (layer-1 operands)
  split_kernel<<<(int)(NF / 4 + 255) / 256, 256, 0, stream>>>(x, xhi, xlo, (int)(NF / 4));

  // weight pre-pack, all 4 matrices in one launch
  PackArgs pa;
  pa.src[0] = W1; pa.hi[0] = w1hi; pa.lo[0] = w1lo;
  pa.src[1] = R1; pa.hi[1] = r1hi; pa.lo[1] = r1lo;
  pa.src[2] = W2; pa.hi[2] = w2hi; pa.lo[2] = w2lo;
  pa.src[3] = R2; pa.hi[3] = r2hi; pa.lo[3] = r2lo;
  pack_all<<<32, 256, 0, stream>>>(pa);

  // CSR build (once per call; edge_index restored before every timed launch)
  hipMemsetAsync(cnt, 0, sizeof(int) * NNODES, stream);
  count_kernel<<<(NEDGES + 255) / 256, 256, 0, stream>>>(dst, cnt, NEDGES);
  scan_partial<<<NPART, 256, 0, stream>>>(cnt, part, NNODES);
  scan_root<<<1, 256, 0, stream>>>(part, pscan, &rs[NNODES], NPART);
  scan_apply<<<NPART, 256, 0, stream>>>(cnt, pscan, rs, cursor, NNODES);
  fill_kernel<<<(NEDGES + 255) / 256, 256, 0, stream>>>(src, dst, cursor, csr, NEDGES);

  const int gemm_grid = (NNODES + 127) / 128;  // 391

  auto layer = [&](const unsigned short* hhi, const unsigned short* hlo,
                   const unsigned short* whi, const unsigned short* wlo,
                   const unsigned short* rhi, const unsigned short* rlo,
                   const float* b, float* outf, unsigned short* ohi, unsigned short* olo) {
    agg_kernel<<<(NNODES + 3) / 4, 256, 0, stream>>>(
        (const unsigned int*)hhi, rs, csr, (unsigned int*)aggb, NNODES);
    gemm_mfma<<<gemm_grid, 256, 0, stream>>>(aggb, hhi, hlo, whi, wlo, rhi, rlo,
                                             b, outf, ohi, olo, NNODES);
  };

  layer(xhi,  xlo,  w1hi, w1lo, r1hi, r1lo, b1, nullptr, hAhi, hAlo);
  layer(hAhi, hAlo, w2hi, w2lo, r2hi, r2lo, b2, nullptr, hBhi, hBlo);
  layer(hBhi, hBlo, w2hi, w2lo, r2hi, r2lo, b2, nullptr, hAhi, hAlo);
  layer(hAhi, hAlo, w2hi, w2lo, r2hi, r2lo, b2, out, nullptr, nullptr);
}